// Round 13
// baseline (49.589 us; speedup 1.0000x reference)
//
#include <hip/hip_runtime.h>

// Slab-ocean 1D explicit Euler, parallel-in-time via ring-down truncation.
//   z = U + iV,  z_{n+1} = a*z_n + b_n,  a = (1 - dt*K1) + i*(-dt*fc) const.
// Hour-level: z_{k+1} = A z_k + S_k,  A = a^60,  S_k = cA*w_k + cB*w_{k+1}.
// |A| <= ~0.67: z_k = sum_m E_m w_m over the last NW=32 samples (truncation
// ~6e-7, 3 decades under the 4.88e-4 fp32 noise floor every round has shown).
//
// r12 post-mortem (49.0 us best): CG=2 gain was only -1.6 us -> stage-1 was
// ~3 us; residue is the write phase (~31 us vs 24 us fill-rate floor). CG=2
// worsened per-CU store imbalance yet still won -> write is PROBABLY
// aggregate-bound, but the per-CU-tail model predicts 8-10 us here. THIS
// ROUND tests exactly that: ROW-BALANCED grid.
//   - 504 blocks x 80 rows each (504*80 = 40320 exact; 504 = 8*63 ->
//     bijective XCD swizzle; ~2 blocks/CU, max 640 KB stores/CU vs 630 avg
//     -- near-perfect, vs r12's 960/630).
//   - rows start mid-chunk (s0 in {0,20,40}): window-sum z at chunk k0
//     start (r12-verified path), PRIME s0 unstored steps (<=40, ~1 us),
//     then two uniform stored segments: n1=60-s0 rows of k0, n2=80-n1 of
//     k0+1 (exact chaining, r6-proven; no mid-loop branch).
// Pre-committed: <=46 tail theory real; 47.5-51 null -> aggregate-bound,
// declare structural next; >=52 revert to r12.
// Keep: gload_lds staging + both-sides XOR swizzle, register weight table,
// z-exchange, NT float4 stores, single plain launch.

#define NT    40320
#define BPTS  1024
#define NF    672
#define NSUB  60
#define CH    60                 // steps per chunk = 1 forcing hour
#define NCH   (NT / CH)          // 672
#define RPB   80                 // rows per block
#define NBLK  (NT / RPB)         // 504 blocks
#define PPT   4                  // points per thread in write -> float4 stores
#define NW    32                 // window samples loaded (8 float4)
#define NV    (NW / 4)           // 8 float4 vectors per row
#define TP    256                // points per staging tile
#define NTILE (BPTS / TP)        // 4 tiles
#define NXCD  8
#define BPX   (NBLK / NXCD)      // 63 blocks per XCD (exact)

typedef float vf4 __attribute__((ext_vector_type(4)));

__device__ __forceinline__ void gload_lds16(const float* g, float* l) {
    __builtin_amdgcn_global_load_lds(
        (const __attribute__((address_space(1))) void*)g,
        (__attribute__((address_space(3))) void*)l, 16, 0, 0);
}

__global__ __launch_bounds__(256, 2)
void slab_chunk(const float* __restrict__ pk,
                const float* __restrict__ TAx,
                const float* __restrict__ TAy,
                const float* __restrict__ fcp,
                const int* __restrict__ dtp,
                float* __restrict__ out) {
    // Bijective XCD swizzle (504 = 8*63): contiguous 63-block row-range/XCD.
    const int bid = blockIdx.x;
    const int swz = (bid & (NXCD - 1)) * BPX + (bid >> 3);
    const int g0  = swz * RPB;            // first output row of this block
    const int k0  = g0 / CH;              // starting chunk
    const int s0  = g0 - k0 * CH;         // starting substep in {0,20,40}
    const int tid = threadIdx.x;

    // ---- model coefficients ----
    const float dtf = (float)dtp[0];
    const float K0  = expf(pk[0]);
    const float K1  = expf(pk[1]);
    const float ar  = 1.0f - dtf * K1;    // Re(a)
    const float ai  = -dtf * fcp[0];      // Im(a)
    const float bs  = dtf * K0;           // forcing scale

    // g1 = sum a^m, g2 = sum ((59-m)/60) a^m, A = a^60  (one 60-iter pass)
    float g1r = 0.f, g1i = 0.f, g2r = 0.f, g2i = 0.f;
    float pr = 1.f, pi = 0.f;
    for (int m = 0; m < NSUB; ++m) {
        g1r += pr; g1i += pi;
        float w = (float)(NSUB - 1 - m) * (1.0f / NSUB);
        g2r = fmaf(w, pr, g2r); g2i = fmaf(w, pi, g2i);
        float nr = pr * ar - pi * ai;
        float ni = pr * ai + pi * ar;
        pr = nr; pi = ni;
    }
    const float Ar  = pr,        Ai  = pi;          // A = a^CH
    const float cAr = g1r - g2r, cAi = g1i - g2i;   // coeff of w_k     in S_k
    const float cBr = g2r,       cBi = g2i;         // coeff of w_{k+1} in S_k
    const float cCr = cAr + (Ar * cBr - Ai * cBi);  // cC = cA + A*cB
    const float cCi = cAi + (Ar * cBi + Ai * cBr);

    // ---- window geometry for chunk k0: samples [ja, ja+NW), 4-aligned ----
    int va = (k0 + 4) & ~3;               // aligned exclusive end, va-1 >= k0
    if (va > NF) va = NF;
    const int ja = va - NW;               // may be negative (zero-weight slots)

    // ---- register weight table (fully unrolled -> stays in VGPRs) ----
    float wgtR[NW], wgtI[NW];
    {
        float Wr = 1.f, Wi = 0.f;         // tracks A^{k0-1-m}; =1 at m=k0-1
#pragma unroll
        for (int i = NW - 1; i >= 0; --i) {
            const int m = ja + i;
            float er = 0.f, ei = 0.f;
            if (k0 > 0 && m >= 0 && m <= k0) {
                if (m == k0) { er = cBr; ei = cBi; }
                else {
                    const float br = (m == 0) ? cAr : cCr;
                    const float bi = (m == 0) ? cAi : cCi;
                    er = Wr * br - Wi * bi;
                    ei = Wr * bi + Wi * br;
                    const float t2 = Wr * Ar - Wi * Ai;
                    Wi = Wr * Ai + Wi * Ar; Wr = t2;
                }
            }
            wgtR[i] = er; wgtI[i] = ei;
        }
    }

    // ---- stage 1: global_load_lds-staged window -> per-point z_{k0} ----
    // Linear LDS [256 pts][32 smp]; slot (r,u) holds global vec u^(r&7).
    __shared__ float ldsx[TP][NW];        // 32 KB
    __shared__ float ldsy[TP][NW];        // 32 KB
    float zr4[NTILE], zi4[NTILE];

#pragma unroll
    for (int tau = 0; tau < NTILE; ++tau) {
#pragma unroll
        for (int it = 0; it < NV; ++it) {
            const int V  = tid + 256 * it;    // 0..2047
            const int r  = V >> 3;
            const int u  = V & 7;
            const int uu = u ^ (r & 7);       // pre-swizzled source vec
            int off = ja + 4 * uu; if (off < 0) off = 0;  // clamp (zero-weight)
            const size_t gb = (size_t)(tau * TP + r) * NF + off;
            gload_lds16(TAx + gb, &ldsx[0][0] + (size_t)V * 4);
            gload_lds16(TAy + gb, &ldsy[0][0] + (size_t)V * 4);
        }
        __syncthreads();                  // drains vmcnt before barrier

        float aR = 0.f, aI = 0.f;
#pragma unroll
        for (int v = 0; v < NV; ++v) {
            const int sv = v ^ (tid & 7);     // swizzled slot for global vec v
            const vf4 fx = *(const vf4*)&ldsx[tid][4 * sv];
            const vf4 fy = *(const vf4*)&ldsy[tid][4 * sv];
#pragma unroll
            for (int e = 0; e < 4; ++e) {
                const int i = 4 * v + e;
                aR = fmaf(wgtR[i], fx[e], fmaf(-wgtI[i], fy[e], aR));
                aI = fmaf(wgtR[i], fy[e], fmaf( wgtI[i], fx[e], aI));
            }
        }
        zr4[tau] = bs * aR; zi4[tau] = bs * aI;
        __syncthreads();                  // before next tile overwrites LDS
    }

    // ---- z-exchange: interleaved ownership -> consecutive p0=4*tid ----
    float2* zbuf = (float2*)&ldsx[0][0];  // 8 KB in dead tile LDS
#pragma unroll
    for (int tau = 0; tau < NTILE; ++tau)
        zbuf[tau * TP + tid] = make_float2(zr4[tau], zi4[tau]);
    __syncthreads();

    const int p0 = tid * PPT;
    float zr[PPT], zi[PPT];
#pragma unroll
    for (int j = 0; j < PPT; ++j) {
        float2 z = zbuf[p0 + j];
        zr[j] = z.x; zi[j] = z.y;
    }

    // ---- stage 2: prime s0 steps, then 80 stored rows (2 segments) ----
    const int f1a = (k0 + 1 < NF) ? k0 + 1 : NF - 1;
    float x1[PPT], y1[PPT], bx[PPT], by[PPT], dbx[PPT], dby[PPT];
#pragma unroll
    for (int j = 0; j < PPT; ++j) {
        const float* rx = TAx + (size_t)(p0 + j) * NF;
        const float* ry = TAy + (size_t)(p0 + j) * NF;
        const float x0 = rx[k0], y0 = ry[k0];
        x1[j] = rx[f1a]; y1[j] = ry[f1a];
        bx[j]  = bs * x0;
        by[j]  = bs * y0;
        dbx[j] = bs * (x1[j] - x0) * (1.0f / NSUB);
        dby[j] = bs * (y1[j] - y0) * (1.0f / NSUB);
    }

    // prime: advance to substep s0 of chunk k0 (no stores)
    for (int s = 0; s < s0; ++s) {
#pragma unroll
        for (int j = 0; j < PPT; ++j) {
            const float ur = fmaf(ar, zr[j], fmaf(-ai, zi[j], bx[j]));
            const float vi = fmaf(ar, zi[j], fmaf( ai, zr[j], by[j]));
            zr[j] = ur; zi[j] = vi;
            bx[j] += dbx[j]; by[j] += dby[j];
        }
    }

    float* orow = out + (size_t)g0 * BPTS + p0;

    // segment 1: n1 = 60 - s0 rows complete chunk k0
    const int n1 = CH - s0;
#pragma unroll 10
    for (int s = 0; s < n1; ++s) {
#pragma unroll
        for (int j = 0; j < PPT; ++j) {
            const float ur = fmaf(ar, zr[j], fmaf(-ai, zi[j], bx[j]));
            const float vi = fmaf(ar, zi[j], fmaf( ai, zr[j], by[j]));
            zr[j] = ur; zi[j] = vi;
            bx[j] += dbx[j]; by[j] += dby[j];
        }
        vf4 v; v.x = zr[0]; v.y = zr[1]; v.z = zr[2]; v.w = zr[3];
        __builtin_nontemporal_store(v, (vf4*)orow);
        orow += BPTS;
    }

    // switch forcing to chunk k1 = k0+1 (x0 <- old x1, reload x1)
    const int k1  = k0 + 1;
    const int f1b = (k1 + 1 < NF) ? k1 + 1 : NF - 1;
#pragma unroll
    for (int j = 0; j < PPT; ++j) {
        const float* rx = TAx + (size_t)(p0 + j) * NF;
        const float* ry = TAy + (size_t)(p0 + j) * NF;
        const float x0 = x1[j], y0 = y1[j];
        const float xn = rx[f1b], yn = ry[f1b];
        bx[j]  = bs * x0;
        by[j]  = bs * y0;
        dbx[j] = bs * (xn - x0) * (1.0f / NSUB);
        dby[j] = bs * (yn - y0) * (1.0f / NSUB);
    }

    // segment 2: n2 = 80 - n1 rows into chunk k1
    const int n2 = RPB - n1;
#pragma unroll 10
    for (int s = 0; s < n2; ++s) {
#pragma unroll
        for (int j = 0; j < PPT; ++j) {
            const float ur = fmaf(ar, zr[j], fmaf(-ai, zi[j], bx[j]));
            const float vi = fmaf(ar, zi[j], fmaf( ai, zr[j], by[j]));
            zr[j] = ur; zi[j] = vi;
            bx[j] += dbx[j]; by[j] += dby[j];
        }
        vf4 v; v.x = zr[0]; v.y = zr[1]; v.z = zr[2]; v.w = zr[3];
        __builtin_nontemporal_store(v, (vf4*)orow);
        orow += BPTS;
    }
}

extern "C" void kernel_launch(void* const* d_in, const int* in_sizes, int n_in,
                              void* d_out, int out_size, void* d_ws, size_t ws_size,
                              hipStream_t stream) {
    const float* pk  = (const float*)d_in[0];
    const float* TAx = (const float*)d_in[1];
    const float* TAy = (const float*)d_in[2];
    const float* fcp = (const float*)d_in[3];
    const int*   dtp = (const int*)d_in[5];   // dt = 60
    float* out = (float*)d_out;

    slab_chunk<<<NBLK, 256, 0, stream>>>(pk, TAx, TAy, fcp, dtp, out);
}